// Round 4
// baseline (1398.247 us; speedup 1.0000x reference)
//
#include <hip/hip_runtime.h>
#include <cstdint>
#include <cmath>

// Problem constants
static constexpr int V_  = 50000;
static constexpr int E_  = 300;
static constexpr int C_  = 128;
static constexpr int B_  = 128;
static constexpr int SC_ = 512;
static constexpr int SE_ = 64;
static constexpr int NCOL = 768;   // [fw_gate 256 | fw_cand 128 | bw_gate 256 | bw_cand 128]
static constexpr int KP  = 320;    // K padded to 10 x 32 for MFMA

// ws layout (float offsets)
static constexpr size_t OFF_PROJ  = 0;
static constexpr size_t SZ_PROJ   = (size_t)V_ * NCOL;
static constexpr size_t OFF_WXP   = OFF_PROJ + SZ_PROJ;
static constexpr size_t SZ_WXP    = (size_t)304 * NCOL;
static constexpr size_t OFF_UALL  = OFF_WXP + SZ_WXP;
static constexpr size_t SZ_UALL   = (size_t)C_ * NCOL;
static constexpr size_t OFF_BIAS  = OFF_UALL + SZ_UALL;
static constexpr size_t SZ_BIAS   = NCOL;
static constexpr size_t OFF_ST    = OFF_BIAS + SZ_BIAS;
static constexpr size_t SZ_ST_CTX = (size_t)B_ * SC_ * C_;
static constexpr size_t SZ_ST_END = (size_t)B_ * SE_ * C_;
static constexpr size_t SZ_ST     = 2*SZ_ST_CTX + 2*SZ_ST_END;    // 75.5 MB
static constexpr size_t OFF_FEATS = OFF_ST + SZ_ST;
static constexpr size_t SZ_FEATS  = (size_t)B_ * 512;
static constexpr size_t OFF_BT    = OFF_FEATS + SZ_FEATS;
// A_hi/A_lo (bf16) OVERLAP the states region (dead once gemm ends; recur
// zeroes its own tail rows so no global memset is needed).

typedef __attribute__((ext_vector_type(8))) short bf16x8;
typedef __attribute__((ext_vector_type(4))) float f32x4;

static __device__ __forceinline__ unsigned short f2bf_rne(float f) {
  unsigned u = __float_as_uint(f);
  unsigned r = u + 0x7fffu + ((u >> 16) & 1u);
  return (unsigned short)(r >> 16);
}

static __device__ __forceinline__ void gload_lds16(const short* g, short* l) {
  __builtin_amdgcn_global_load_lds(
      (const __attribute__((address_space(1))) void*)g,
      (__attribute__((address_space(3))) void*)l, 16, 0, 0);
}

// ---------------------------------------------------------------------------
// Pack: Wxp[304][768] fp32, Uall[128][768], bias[768]
// ---------------------------------------------------------------------------
__global__ void pack_kernel(const float* __restrict__ fw_gw, const float* __restrict__ fw_gb,
                            const float* __restrict__ fw_cw, const float* __restrict__ fw_cb,
                            const float* __restrict__ bw_gw, const float* __restrict__ bw_gb,
                            const float* __restrict__ bw_cw, const float* __restrict__ bw_cb,
                            float* __restrict__ ws) {
  int i = blockIdx.x * 256 + threadIdx.x;
  float* Wxp  = ws + OFF_WXP;
  float* Uall = ws + OFF_UALL;
  float* bias = ws + OFF_BIAS;
  if (i < 304 * NCOL) {
    int k = i / NCOL, c = i % NCOL;
    float v = 0.f;
    if (k < 300) {
      if (c < 256)      v = fw_gw[k*256 + c];
      else if (c < 384) v = fw_cw[k*128 + (c-256)];
      else if (c < 640) v = bw_gw[k*256 + (c-384)];
      else              v = bw_cw[k*128 + (c-640)];
    }
    Wxp[i] = v;
    return;
  }
  int j = i - 304 * NCOL;
  if (j >= 0 && j < 128 * NCOL) {
    int k = j / NCOL, c = j % NCOL;
    int kk = 300 + k;
    float v;
    if (c < 256)      v = fw_gw[kk*256 + c];
    else if (c < 384) v = fw_cw[kk*128 + (c-256)];
    else if (c < 640) v = bw_gw[kk*256 + (c-384)];
    else              v = bw_cw[kk*128 + (c-640)];
    Uall[j] = v;
    return;
  }
  int m = j - 128 * NCOL;
  if (m >= 0 && m < NCOL) {
    float v;
    if (m < 256)      v = fw_gb[m];
    else if (m < 384) v = fw_cb[m-256];
    else if (m < 640) v = bw_gb[m-384];
    else              v = bw_cb[m-640];
    bias[m] = v;
  }
}

__global__ void pack_bt(const float* __restrict__ Wxp, short* __restrict__ Bthi,
                        short* __restrict__ Btlo) {
  int i = blockIdx.x * 256 + threadIdx.x;
  if (i >= NCOL * KP) return;
  int k = i % KP, n = i / KP;
  float v = (k < 304) ? Wxp[(size_t)k * NCOL + n] : 0.f;
  unsigned short h = f2bf_rne(v);
  float hf = __uint_as_float((unsigned)h << 16);
  unsigned short lo = f2bf_rne(v - hf);
  Bthi[i] = (short)h;
  Btlo[i] = (short)lo;
}

__global__ void pack_emb(const float* __restrict__ emb, short* __restrict__ Ahi,
                         short* __restrict__ Alo) {
  size_t i = (size_t)blockIdx.x * 256 + threadIdx.x;
  if (i >= (size_t)V_ * KP) return;
  int k = (int)(i % KP);
  size_t row = i / KP;
  float v = (k < E_) ? emb[row * E_ + k] : 0.f;
  unsigned short h = f2bf_rne(v);
  float hf = __uint_as_float((unsigned)h << 16);
  unsigned short lo = f2bf_rne(v - hf);
  Ahi[i] = (short)h;
  Alo[i] = (short)lo;
}

// ---------------------------------------------------------------------------
// proj = emb @ Wxp via bf16x3 split MFMA (m97 structure)
// ---------------------------------------------------------------------------
__global__ __launch_bounds__(256) void gemm_mfma(
    const short* __restrict__ Ahi, const short* __restrict__ Alo,
    const short* __restrict__ Bthi, const short* __restrict__ Btlo,
    float* __restrict__ proj) {
  __shared__ short lds[16384];
  int tid = threadIdx.x, wid = tid >> 6, lane = tid & 63;
  int n0 = blockIdx.x * 128, m0 = blockIdx.y * 128;
  f32x4 acc[4][4] = {};

  int lr = lane >> 2, lc = lane & 3;
  int q0 = wid * 2, q1 = q0 + 1;
  int r0 = q0 * 16 + lr, r1 = q1 * 16 + lr;
  int am0 = m0 + r0; if (am0 > V_ - 1) am0 = V_ - 1;
  int am1 = m0 + r1; if (am1 > V_ - 1) am1 = V_ - 1;
  size_t gaOff0 = (size_t)am0 * KP + lc * 8;
  size_t gaOff1 = (size_t)am1 * KP + lc * 8;
  size_t gbOff0 = (size_t)(n0 + r0) * KP + lc * 8;
  size_t gbOff1 = (size_t)(n0 + r1) * KP + lc * 8;

  int quad = lane >> 4;
  int arow = (wid >> 1) * 64 + (lane & 15);
  int brow = (wid & 1) * 64 + (lane & 15);

  for (int k0 = 0; k0 < KP; k0 += 32) {
    gload_lds16(Ahi  + gaOff0 + k0, lds +         q0 * 512);
    gload_lds16(Ahi  + gaOff1 + k0, lds +         q1 * 512);
    gload_lds16(Alo  + gaOff0 + k0, lds +  4096 + q0 * 512);
    gload_lds16(Alo  + gaOff1 + k0, lds +  4096 + q1 * 512);
    gload_lds16(Bthi + gbOff0 + k0, lds +  8192 + q0 * 512);
    gload_lds16(Bthi + gbOff1 + k0, lds +  8192 + q1 * 512);
    gload_lds16(Btlo + gbOff0 + k0, lds + 12288 + q0 * 512);
    gload_lds16(Btlo + gbOff1 + k0, lds + 12288 + q1 * 512);
    __syncthreads();

    bf16x8 ah[4], al[4], bh[4], bl[4];
#pragma unroll
    for (int i = 0; i < 4; ++i) {
      ah[i] = *(bf16x8*)&lds[        (arow + i*16) * 32 + quad * 8];
      al[i] = *(bf16x8*)&lds[ 4096 + (arow + i*16) * 32 + quad * 8];
      bh[i] = *(bf16x8*)&lds[ 8192 + (brow + i*16) * 32 + quad * 8];
      bl[i] = *(bf16x8*)&lds[12288 + (brow + i*16) * 32 + quad * 8];
    }
#pragma unroll
    for (int i = 0; i < 4; ++i)
#pragma unroll
      for (int j = 0; j < 4; ++j) {
        acc[i][j] = __builtin_amdgcn_mfma_f32_16x16x32_bf16(ah[i], bh[j], acc[i][j], 0, 0, 0);
        acc[i][j] = __builtin_amdgcn_mfma_f32_16x16x32_bf16(ah[i], bl[j], acc[i][j], 0, 0, 0);
        acc[i][j] = __builtin_amdgcn_mfma_f32_16x16x32_bf16(al[i], bh[j], acc[i][j], 0, 0, 0);
      }
    __syncthreads();
  }

  int colb = n0 + (wid & 1) * 64 + (lane & 15);
  int rowb = m0 + (wid >> 1) * 64 + quad * 4;
#pragma unroll
  for (int i = 0; i < 4; ++i) {
    int rb = rowb + i * 16;
#pragma unroll
    for (int j = 0; j < 4; ++j) {
      int cc = colb + j * 16;
#pragma unroll
      for (int r = 0; r < 4; ++r) {
        int rr = rb + r;
        if (rr < V_) proj[(size_t)rr * NCOL + cc] = acc[i][j][r];
      }
    }
  }
}

// ---------------------------------------------------------------------------
// Recurrence v4: 512 threads (8 waves). Wave w owns k-slice [16w,16w+16).
// Gate: lane (kq=l&1, jq=l>>1) does 8k x 8j micro-dot (64 FMA, 64 weight VGPRs).
// Cand: lane (kq2=l&3, jq2=l>>2) does 4k x 8j (32 FMA, 32 weight VGPRs).
// Cross-kq reduce via shfl_xor (DPP quad); cross-wave via small LDS partials.
// 4 barriers/step; ~2 LDS reads + 2 masked LDS writes per wave per step.
// ---------------------------------------------------------------------------
__global__ __launch_bounds__(512, 4) void recur_kernel(
    const int* __restrict__ ctx, const int* __restrict__ endseq,
    const int* __restrict__ ctx_len, const int* __restrict__ end_len,
    const float* __restrict__ proj, const float* __restrict__ Uall,
    const float* __restrict__ bias, float* __restrict__ states) {
  __shared__ __align__(16) float h_s[128];
  __shared__ __align__(16) float rh_s[128];
  __shared__ __align__(16) float u_s[128];
  __shared__ __align__(16) float pg[8][258];
  __shared__ __align__(16) float pc[8][258];

  int bid = blockIdx.x;
  int tid = threadIdx.x;
  const int* seq; int S, L, b, dir; float* stbase;
  if (bid < 256) {
    b = bid >> 1; dir = bid & 1;
    seq = ctx + b * SC_; S = SC_; L = ctx_len[b];
    stbase = states + (dir ? SZ_ST_CTX : 0) + (size_t)b * SC_ * C_;
  } else {
    int q = bid - 256; b = q >> 1; dir = q & 1;
    seq = endseq + b * SE_; S = SE_; L = end_len[b];
    stbase = states + 2*SZ_ST_CTX + (dir ? SZ_ST_END : 0) + (size_t)b * SE_ * C_;
  }
  int dirOff = dir ? 384 : 0;
  int w = tid >> 6, lane = tid & 63;
  int kq  = lane & 1, jq  = lane >> 1;   // gate micro-tile coords
  int kq2 = lane & 3, jq2 = lane >> 2;   // cand micro-tile coords
  int gk0 = w * 16 + kq * 8,  gj0 = jq * 8;
  int ck0 = w * 16 + kq2 * 4, cj0 = jq2 * 8;

  // gate weights 8k x 8j (64 VGPRs)
  float wgt[8][8];
#pragma unroll
  for (int kk = 0; kk < 8; ++kk) {
    const float* up = Uall + (size_t)(gk0 + kk) * NCOL + dirOff + gj0;
    float4 w0 = *(const float4*)(up);
    float4 w1 = *(const float4*)(up + 4);
    wgt[kk][0]=w0.x; wgt[kk][1]=w0.y; wgt[kk][2]=w0.z; wgt[kk][3]=w0.w;
    wgt[kk][4]=w1.x; wgt[kk][5]=w1.y; wgt[kk][6]=w1.z; wgt[kk][7]=w1.w;
  }
  // cand weights 4k x 8j (32 VGPRs)
  float wct[4][8];
#pragma unroll
  for (int kk = 0; kk < 4; ++kk) {
    const float* up = Uall + (size_t)(ck0 + kk) * NCOL + dirOff + 256 + cj0;
    float4 w0 = *(const float4*)(up);
    float4 w1 = *(const float4*)(up + 4);
    wct[kk][0]=w0.x; wct[kk][1]=w0.y; wct[kk][2]=w0.z; wct[kk][3]=w0.w;
    wct[kk][4]=w1.x; wct[kk][5]=w1.y; wct[kk][6]=w1.z; wct[kk][7]=w1.w;
  }

  float bias_g = (tid < 256) ? bias[dirOff + tid] : 0.f;
  float bias_c = (tid < 128) ? bias[dirOff + 256 + tid] : 0.f;

  if (tid < 128) h_s[tid] = 0.f;
  __syncthreads();

  // prefetch step 0's x-projection
  int pos0 = dir ? (L - 1) : 0;
  int tok0 = seq[pos0];
  const float* xr0 = proj + (size_t)tok0 * NCOL + dirOff;
  float xg = (tid < 256) ? xr0[tid] : 0.f;
  float xc = (tid < 128) ? xr0[256 + tid] : 0.f;

  for (int t = 0; t < L; ++t) {
    // prefetch next step's x-projection (hidden behind this step)
    float xg_n = 0.f, xc_n = 0.f;
    if (t + 1 < L) {
      int pos_n = dir ? (L - 2 - t) : (t + 1);
      int tok_n = seq[pos_n];
      const float* xr = proj + (size_t)tok_n * NCOL + dirOff;
      if (tid < 256) xg_n = xr[tid];
      if (tid < 128) xc_n = xr[256 + tid];
    }

    // --- gate partials: 8k x 8j ---
    float4 hv0 = *(const float4*)(&h_s[gk0]);
    float4 hv1 = *(const float4*)(&h_s[gk0 + 4]);
    float he[8] = {hv0.x, hv0.y, hv0.z, hv0.w, hv1.x, hv1.y, hv1.z, hv1.w};
    float acc[8] = {};
#pragma unroll
    for (int kk = 0; kk < 8; ++kk)
#pragma unroll
      for (int jj = 0; jj < 8; ++jj)
        acc[jj] += he[kk] * wgt[kk][jj];
#pragma unroll
    for (int jj = 0; jj < 8; ++jj)
      acc[jj] += __shfl_xor(acc[jj], 1, 64);     // reduce kq (DPP quad)
    if (kq == 0) {
      *(float4*)(&pg[w][gj0])     = make_float4(acc[0], acc[1], acc[2], acc[3]);
      *(float4*)(&pg[w][gj0 + 4]) = make_float4(acc[4], acc[5], acc[6], acc[7]);
    }
    __syncthreads();   // B1

    // --- gate consume: j = tid (<256) ---
    float g = 0.f;
    if (tid < 256) {
      g = xg + bias_g;
#pragma unroll
      for (int w2 = 0; w2 < 8; ++w2) g += pg[w2][tid];
      g = 1.f / (1.f + expf(-g));
      if (tid < 128) rh_s[tid] = g * h_s[tid];   // r * h_old
      else           u_s[tid - 128] = g;         // u
    }
    __syncthreads();   // B2

    // --- cand partials: 4k x 8j ---
    float4 rv = *(const float4*)(&rh_s[ck0]);
    float re[4] = {rv.x, rv.y, rv.z, rv.w};
    float ac2[8] = {};
#pragma unroll
    for (int kk = 0; kk < 4; ++kk)
#pragma unroll
      for (int jj = 0; jj < 8; ++jj)
        ac2[jj] += re[kk] * wct[kk][jj];
#pragma unroll
    for (int jj = 0; jj < 8; ++jj)
      ac2[jj] += __shfl_xor(ac2[jj], 1, 64);
#pragma unroll
    for (int jj = 0; jj < 8; ++jj)
      ac2[jj] += __shfl_xor(ac2[jj], 2, 64);
    if (kq2 == 0) {
      *(float4*)(&pc[w][cj0])     = make_float4(ac2[0], ac2[1], ac2[2], ac2[3]);
      *(float4*)(&pc[w][cj0 + 4]) = make_float4(ac2[4], ac2[5], ac2[6], ac2[7]);
    }
    __syncthreads();   // B3

    // --- cand consume + h update: j = tid (<128) ---
    if (tid < 128) {
      float cs = xc + bias_c;
#pragma unroll
      for (int w2 = 0; w2 < 8; ++w2) cs += pc[w2][tid];
      float c = tanhf(cs);
      float u = u_s[tid];
      float ho = h_s[tid];
      float hn = u * ho + (1.f - u) * c;
      h_s[tid] = hn;
      int pos = dir ? (L - 1 - t) : t;
      stbase[(size_t)pos * C_ + tid] = hn;
    }
    __syncthreads();   // B4
    xg = xg_n; xc = xc_n;
  }

  // zero tail rows [L, S) — replaces the global memset of states
  for (int i = L * C_ + tid; i < S * C_; i += 512) stbase[i] = 0.f;
}

// ---------------------------------------------------------------------------
// Attention: one WG per (b, array); flash-style online softmax.
// ---------------------------------------------------------------------------
__global__ __launch_bounds__(256, 2) void attn_kernel(
    const float* __restrict__ states, const float* __restrict__ att_v,
    const float* __restrict__ att_w, const float* __restrict__ att_b,
    float* __restrict__ feats) {
  __shared__ __align__(16) float st_s[8][132];
  __shared__ __align__(16) float pgA[8][8][132];
  __shared__ float score_s[8];
  __shared__ float cm[128], cl[128], ca[128];

  int bid = blockIdx.x, tid = threadIdx.x;
  int b, dir, S, featOff; const float* stb;
  if (bid < 256) {
    b = bid >> 1; dir = bid & 1; S = SC_;
    stb = states + (dir ? SZ_ST_CTX : 0) + (size_t)b * SC_ * C_;
    featOff = dir * 128;
  } else {
    int q = bid - 256; b = q >> 1; dir = q & 1; S = SE_;
    stb = states + 2*SZ_ST_CTX + (dir ? SZ_ST_END : 0) + (size_t)b * SE_ * C_;
    featOff = 256 + dir * 128;
  }

  int kg = tid >> 5, jg = tid & 31;
  float wreg[16][4];
#pragma unroll
  for (int kk = 0; kk < 16; ++kk) {
    float4 wv = *(const float4*)(att_w + (size_t)(kg*16 + kk) * C_ + jg*4);
    wreg[kk][0]=wv.x; wreg[kk][1]=wv.y; wreg[kk][2]=wv.z; wreg[kk][3]=wv.w;
  }
  int d0 = jg * 4;
  float4 b4 = *(const float4*)(att_b + d0);
  float4 v4 = *(const float4*)(att_v + d0);
  int c = tid & 127, half = tid >> 7;

  float m = -1e30f, lsum = 0.f, acc = 0.f;

  for (int s0 = 0; s0 < S; s0 += 8) {
    __syncthreads();
    for (int lId = tid; lId < 1024; lId += 256) {
      int r = lId >> 7, k = lId & 127;
      st_s[r][k] = stb[(size_t)(s0 + r) * C_ + k];
    }
    __syncthreads();

    float pacc[8][4] = {};
#pragma unroll
    for (int r = 0; r < 8; ++r) {
      const float4* srow4 = (const float4*)(&st_s[r][0]);
#pragma unroll
      for (int q = 0; q < 4; ++q) {
        float4 sv = srow4[kg*4 + q];
        float se[4] = {sv.x, sv.y, sv.z, sv.w};
#pragma unroll
        for (int e = 0; e < 4; ++e)
#pragma unroll
          for (int jj = 0; jj < 4; ++jj)
            pacc[r][jj] += se[e] * wreg[q*4 + e][jj];
      }
    }
#pragma unroll
    for (int r = 0; r < 8; ++r)
      *(float4*)(&pgA[kg][r][jg*4]) =
          make_float4(pacc[r][0], pacc[r][1], pacc[r][2], pacc[r][3]);
    __syncthreads();

    float4 p4 = make_float4(0.f, 0.f, 0.f, 0.f);
#pragma unroll
    for (int k2 = 0; k2 < 8; ++k2) {
      float4 t4 = *(const float4*)(&pgA[k2][kg][d0]);
      p4.x += t4.x; p4.y += t4.y; p4.z += t4.z; p4.w += t4.w;
    }
    float sc = tanhf(p4.x + b4.x) * v4.x + tanhf(p4.y + b4.y) * v4.y +
               tanhf(p4.z + b4.z) * v4.z + tanhf(p4.w + b4.w) * v4.w;
#pragma unroll
    for (int off = 16; off > 0; off >>= 1) sc += __shfl_xor(sc, off, 64);
    if (jg == 0) score_s[kg] = sc;
    __syncthreads();

    float srow[8]; float smax = m;
#pragma unroll
    for (int r = 0; r < 8; ++r) { srow[r] = score_s[r]; smax = fmaxf(smax, srow[r]); }
    float scale = expf(m - smax);
    acc *= scale; lsum *= scale; m = smax;
#pragma unroll
    for (int rr = 0; rr < 4; ++rr) {
      int r = half * 4 + rr;
      float w = expf(srow[r] - m);
      lsum += w;
      acc += w * st_s[r][c];
    }
  }

  __syncthreads();
  if (half == 1) { cm[c] = m; cl[c] = lsum; ca[c] = acc; }
  __syncthreads();
  if (half == 0) {
    float m1 = cm[c], l1 = cl[c], a1 = ca[c];
    float M = fmaxf(m, m1);
    float w0 = expf(m - M), w1 = expf(m1 - M);
    feats[b * 512 + featOff + c] = (acc * w0 + a1 * w1) / (lsum * w0 + l1 * w1);
  }
}

// ---------------------------------------------------------------------------
// Head
// ---------------------------------------------------------------------------
__global__ __launch_bounds__(128) void head_kernel(
    const float* __restrict__ feats, const float* __restrict__ hid_w,
    const float* __restrict__ hid_b, const float* __restrict__ out_w,
    const float* __restrict__ out_b, float* __restrict__ out) {
  __shared__ __align__(16) float f_s[512];
  __shared__ float part[2];
  int b = blockIdx.x, tid = threadIdx.x;
  for (int i = tid; i < 512; i += 128) f_s[i] = feats[b * 512 + i];
  __syncthreads();
  float h = hid_b[tid];
  for (int k = 0; k < 512; ++k) h += f_s[k] * hid_w[k * 128 + tid];
  h = fmaxf(h, 0.f);
  float p = h * out_w[tid];
#pragma unroll
  for (int off = 32; off > 0; off >>= 1) p += __shfl_xor(p, off, 64);
  if ((tid & 63) == 0) part[tid >> 6] = p;
  __syncthreads();
  if (tid == 0) out[b] = part[0] + part[1] + out_b[0];
}

// ---------------------------------------------------------------------------
extern "C" void kernel_launch(void* const* d_in, const int* in_sizes, int n_in,
                              void* d_out, int out_size, void* d_ws, size_t ws_size,
                              hipStream_t stream) {
  const int*   ctx     = (const int*)d_in[0];
  const int*   endseq  = (const int*)d_in[1];
  const int*   ctx_len = (const int*)d_in[2];
  const int*   end_len = (const int*)d_in[3];
  const float* emb     = (const float*)d_in[4];
  const float* fw_gw   = (const float*)d_in[5];
  const float* fw_gb   = (const float*)d_in[6];
  const float* fw_cw   = (const float*)d_in[7];
  const float* fw_cb   = (const float*)d_in[8];
  const float* bw_gw   = (const float*)d_in[9];
  const float* bw_gb   = (const float*)d_in[10];
  const float* bw_cw   = (const float*)d_in[11];
  const float* bw_cb   = (const float*)d_in[12];
  const float* att_v   = (const float*)d_in[13];
  const float* att_w   = (const float*)d_in[14];
  const float* att_b   = (const float*)d_in[15];
  const float* hid_w   = (const float*)d_in[16];
  const float* hid_b   = (const float*)d_in[17];
  const float* out_w   = (const float*)d_in[18];
  const float* out_b   = (const float*)d_in[19];
  float* ws  = (float*)d_ws;
  float* out = (float*)d_out;

  short* Ahi  = (short*)(ws + OFF_ST);
  short* Alo  = Ahi + (size_t)V_ * KP;
  short* Bthi = (short*)(ws + OFF_BT);
  short* Btlo = Bthi + (size_t)NCOL * KP;

  pack_kernel<<<1299, 256, 0, stream>>>(fw_gw, fw_gb, fw_cw, fw_cb,
                                        bw_gw, bw_gb, bw_cw, bw_cb, ws);
  pack_bt<<<(NCOL * KP + 255) / 256, 256, 0, stream>>>(ws + OFF_WXP, Bthi, Btlo);
  pack_emb<<<(int)(((size_t)V_ * KP + 255) / 256), 256, 0, stream>>>(emb, Ahi, Alo);

  dim3 ggrid(6, 391);
  gemm_mfma<<<ggrid, 256, 0, stream>>>(Ahi, Alo, Bthi, Btlo, ws + OFF_PROJ);

  recur_kernel<<<512, 512, 0, stream>>>(ctx, endseq, ctx_len, end_len,
                                        ws + OFF_PROJ, ws + OFF_UALL,
                                        ws + OFF_BIAS, ws + OFF_ST);

  attn_kernel<<<512, 256, 0, stream>>>(ws + OFF_ST, att_v, att_w, att_b,
                                       ws + OFF_FEATS);

  head_kernel<<<128, 128, 0, stream>>>(ws + OFF_FEATS, hid_w, hid_b,
                                       out_w, out_b, out);
}

// Round 5
// 910.031 us; speedup vs baseline: 1.5365x; 1.5365x over previous
//
#include <hip/hip_runtime.h>
#include <cstdint>
#include <cmath>

// Problem constants
static constexpr int V_  = 50000;
static constexpr int E_  = 300;
static constexpr int C_  = 128;
static constexpr int B_  = 128;
static constexpr int SC_ = 512;
static constexpr int SE_ = 64;
static constexpr int NCOL = 768;   // [fw_gate 256 | fw_cand 128 | bw_gate 256 | bw_cand 128]
static constexpr int KP  = 320;    // K padded to 10 x 32 for MFMA

// ws layout (float offsets)
static constexpr size_t OFF_PROJ  = 0;
static constexpr size_t SZ_PROJ   = (size_t)V_ * NCOL;
static constexpr size_t OFF_WXP   = OFF_PROJ + SZ_PROJ;
static constexpr size_t SZ_WXP    = (size_t)304 * NCOL;
static constexpr size_t OFF_UALL  = OFF_WXP + SZ_WXP;
static constexpr size_t SZ_UALL   = (size_t)C_ * NCOL;
static constexpr size_t OFF_BIAS  = OFF_UALL + SZ_UALL;
static constexpr size_t SZ_BIAS   = NCOL;
static constexpr size_t OFF_ST    = OFF_BIAS + SZ_BIAS;
static constexpr size_t SZ_ST_CTX = (size_t)B_ * SC_ * C_;
static constexpr size_t SZ_ST_END = (size_t)B_ * SE_ * C_;
static constexpr size_t SZ_ST     = 2*SZ_ST_CTX + 2*SZ_ST_END;    // 75.5 MB
static constexpr size_t OFF_FEATS = OFF_ST + SZ_ST;
static constexpr size_t SZ_FEATS  = (size_t)B_ * 512;
static constexpr size_t OFF_BT    = OFF_FEATS + SZ_FEATS;
// A_hi/A_lo (bf16) OVERLAP the states region (dead once gemm ends; recur
// zeroes its own tail rows so no global memset is needed).

typedef __attribute__((ext_vector_type(8))) short bf16x8;
typedef __attribute__((ext_vector_type(4))) float f32x4;

static __device__ __forceinline__ unsigned short f2bf_rne(float f) {
  unsigned u = __float_as_uint(f);
  unsigned r = u + 0x7fffu + ((u >> 16) & 1u);
  return (unsigned short)(r >> 16);
}

static __device__ __forceinline__ void gload_lds16(const short* g, short* l) {
  __builtin_amdgcn_global_load_lds(
      (const __attribute__((address_space(1))) void*)g,
      (__attribute__((address_space(3))) void*)l, 16, 0, 0);
}

// fast activations: __expf + v_rcp_f32 (~1e-6 rel err; logit threshold 7.4e-5)
static __device__ __forceinline__ float fast_sigmoid(float x) {
  return __builtin_amdgcn_rcpf(1.f + __expf(-x));
}
static __device__ __forceinline__ float fast_tanh(float x) {
  // tanh(x) = 1 - 2/(e^{2x}+1); saturates correctly at +/-inf
  return fmaf(-2.f, __builtin_amdgcn_rcpf(__expf(2.f * x) + 1.f), 1.f);
}

// ---------------------------------------------------------------------------
// Pack: Wxp[304][768] fp32, Uall[128][768], bias[768]
// ---------------------------------------------------------------------------
__global__ void pack_kernel(const float* __restrict__ fw_gw, const float* __restrict__ fw_gb,
                            const float* __restrict__ fw_cw, const float* __restrict__ fw_cb,
                            const float* __restrict__ bw_gw, const float* __restrict__ bw_gb,
                            const float* __restrict__ bw_cw, const float* __restrict__ bw_cb,
                            float* __restrict__ ws) {
  int i = blockIdx.x * 256 + threadIdx.x;
  float* Wxp  = ws + OFF_WXP;
  float* Uall = ws + OFF_UALL;
  float* bias = ws + OFF_BIAS;
  if (i < 304 * NCOL) {
    int k = i / NCOL, c = i % NCOL;
    float v = 0.f;
    if (k < 300) {
      if (c < 256)      v = fw_gw[k*256 + c];
      else if (c < 384) v = fw_cw[k*128 + (c-256)];
      else if (c < 640) v = bw_gw[k*256 + (c-384)];
      else              v = bw_cw[k*128 + (c-640)];
    }
    Wxp[i] = v;
    return;
  }
  int j = i - 304 * NCOL;
  if (j >= 0 && j < 128 * NCOL) {
    int k = j / NCOL, c = j % NCOL;
    int kk = 300 + k;
    float v;
    if (c < 256)      v = fw_gw[kk*256 + c];
    else if (c < 384) v = fw_cw[kk*128 + (c-256)];
    else if (c < 640) v = bw_gw[kk*256 + (c-384)];
    else              v = bw_cw[kk*128 + (c-640)];
    Uall[j] = v;
    return;
  }
  int m = j - 128 * NCOL;
  if (m >= 0 && m < NCOL) {
    float v;
    if (m < 256)      v = fw_gb[m];
    else if (m < 384) v = fw_cb[m-256];
    else if (m < 640) v = bw_gb[m-384];
    else              v = bw_cb[m-640];
    bias[m] = v;
  }
}

__global__ void pack_bt(const float* __restrict__ Wxp, short* __restrict__ Bthi,
                        short* __restrict__ Btlo) {
  int i = blockIdx.x * 256 + threadIdx.x;
  if (i >= NCOL * KP) return;
  int k = i % KP, n = i / KP;
  float v = (k < 304) ? Wxp[(size_t)k * NCOL + n] : 0.f;
  unsigned short h = f2bf_rne(v);
  float hf = __uint_as_float((unsigned)h << 16);
  unsigned short lo = f2bf_rne(v - hf);
  Bthi[i] = (short)h;
  Btlo[i] = (short)lo;
}

__global__ void pack_emb(const float* __restrict__ emb, short* __restrict__ Ahi,
                         short* __restrict__ Alo) {
  size_t i = (size_t)blockIdx.x * 256 + threadIdx.x;
  if (i >= (size_t)V_ * KP) return;
  int k = (int)(i % KP);
  size_t row = i / KP;
  float v = (k < E_) ? emb[row * E_ + k] : 0.f;
  unsigned short h = f2bf_rne(v);
  float hf = __uint_as_float((unsigned)h << 16);
  unsigned short lo = f2bf_rne(v - hf);
  Ahi[i] = (short)h;
  Alo[i] = (short)lo;
}

// ---------------------------------------------------------------------------
// proj = emb @ Wxp via bf16x3 split MFMA (m97 structure)
// ---------------------------------------------------------------------------
__global__ __launch_bounds__(256) void gemm_mfma(
    const short* __restrict__ Ahi, const short* __restrict__ Alo,
    const short* __restrict__ Bthi, const short* __restrict__ Btlo,
    float* __restrict__ proj) {
  __shared__ short lds[16384];
  int tid = threadIdx.x, wid = tid >> 6, lane = tid & 63;
  int n0 = blockIdx.x * 128, m0 = blockIdx.y * 128;
  f32x4 acc[4][4] = {};

  int lr = lane >> 2, lc = lane & 3;
  int q0 = wid * 2, q1 = q0 + 1;
  int r0 = q0 * 16 + lr, r1 = q1 * 16 + lr;
  int am0 = m0 + r0; if (am0 > V_ - 1) am0 = V_ - 1;
  int am1 = m0 + r1; if (am1 > V_ - 1) am1 = V_ - 1;
  size_t gaOff0 = (size_t)am0 * KP + lc * 8;
  size_t gaOff1 = (size_t)am1 * KP + lc * 8;
  size_t gbOff0 = (size_t)(n0 + r0) * KP + lc * 8;
  size_t gbOff1 = (size_t)(n0 + r1) * KP + lc * 8;

  int quad = lane >> 4;
  int arow = (wid >> 1) * 64 + (lane & 15);
  int brow = (wid & 1) * 64 + (lane & 15);

  for (int k0 = 0; k0 < KP; k0 += 32) {
    gload_lds16(Ahi  + gaOff0 + k0, lds +         q0 * 512);
    gload_lds16(Ahi  + gaOff1 + k0, lds +         q1 * 512);
    gload_lds16(Alo  + gaOff0 + k0, lds +  4096 + q0 * 512);
    gload_lds16(Alo  + gaOff1 + k0, lds +  4096 + q1 * 512);
    gload_lds16(Bthi + gbOff0 + k0, lds +  8192 + q0 * 512);
    gload_lds16(Bthi + gbOff1 + k0, lds +  8192 + q1 * 512);
    gload_lds16(Btlo + gbOff0 + k0, lds + 12288 + q0 * 512);
    gload_lds16(Btlo + gbOff1 + k0, lds + 12288 + q1 * 512);
    __syncthreads();

    bf16x8 ah[4], al[4], bh[4], bl[4];
#pragma unroll
    for (int i = 0; i < 4; ++i) {
      ah[i] = *(bf16x8*)&lds[        (arow + i*16) * 32 + quad * 8];
      al[i] = *(bf16x8*)&lds[ 4096 + (arow + i*16) * 32 + quad * 8];
      bh[i] = *(bf16x8*)&lds[ 8192 + (brow + i*16) * 32 + quad * 8];
      bl[i] = *(bf16x8*)&lds[12288 + (brow + i*16) * 32 + quad * 8];
    }
#pragma unroll
    for (int i = 0; i < 4; ++i)
#pragma unroll
      for (int j = 0; j < 4; ++j) {
        acc[i][j] = __builtin_amdgcn_mfma_f32_16x16x32_bf16(ah[i], bh[j], acc[i][j], 0, 0, 0);
        acc[i][j] = __builtin_amdgcn_mfma_f32_16x16x32_bf16(ah[i], bl[j], acc[i][j], 0, 0, 0);
        acc[i][j] = __builtin_amdgcn_mfma_f32_16x16x32_bf16(al[i], bh[j], acc[i][j], 0, 0, 0);
      }
    __syncthreads();
  }

  int colb = n0 + (wid & 1) * 64 + (lane & 15);
  int rowb = m0 + (wid >> 1) * 64 + quad * 4;
#pragma unroll
  for (int i = 0; i < 4; ++i) {
    int rb = rowb + i * 16;
#pragma unroll
    for (int j = 0; j < 4; ++j) {
      int cc = colb + j * 16;
#pragma unroll
      for (int r = 0; r < 4; ++r) {
        int rr = rb + r;
        if (rr < V_) proj[(size_t)rr * NCOL + cc] = acc[i][j][r];
      }
    }
  }
}

// ---------------------------------------------------------------------------
// Recurrence v5: round-1 dataflow (k-sliced partials, 4 barriers/step) with
// weights FORCED register-resident: amdgpu_waves_per_eu(2,2) pins occupancy
// at 2 waves/EU so the RA budget is 256 VGPRs (192 weight floats + temps fit;
// prior rounds spilled weights to scratch and reloaded every step).
// ---------------------------------------------------------------------------
__global__ __attribute__((amdgpu_flat_work_group_size(256, 256),
                          amdgpu_waves_per_eu(2, 2)))
void recur_kernel(
    const int* __restrict__ ctx, const int* __restrict__ endseq,
    const int* __restrict__ ctx_len, const int* __restrict__ end_len,
    const float* __restrict__ proj, const float* __restrict__ Uall,
    const float* __restrict__ bias, float* __restrict__ states) {
  __shared__ __align__(16) float h_s[128];
  __shared__ __align__(16) float rh_s[128];
  __shared__ __align__(16) float u_s[128];
  __shared__ __align__(16) float pg[8][260];
  __shared__ __align__(16) float pc[8][132];

  int bid = blockIdx.x;
  int tid = threadIdx.x;
  const int* seq; int S, L, b, dir; float* stbase;
  if (bid < 256) {
    b = bid >> 1; dir = bid & 1;
    seq = ctx + b * SC_; S = SC_; L = ctx_len[b];
    stbase = states + (dir ? SZ_ST_CTX : 0) + (size_t)b * SC_ * C_;
  } else {
    int q = bid - 256; b = q >> 1; dir = q & 1;
    seq = endseq + b * SE_; S = SE_; L = end_len[b];
    stbase = states + 2*SZ_ST_CTX + (dir ? SZ_ST_END : 0) + (size_t)b * SE_ * C_;
  }
  int dirOff = dir ? 384 : 0;
  int kg = tid >> 5, jg = tid & 31;

  // gate block 16k x 8j (128 VGPRs) + cand block 16k x 4j (64 VGPRs)
  float wg[16][8];
  float wc[16][4];
#pragma unroll
  for (int kk = 0; kk < 16; ++kk) {
    const float* up = Uall + (size_t)(kg*16 + kk) * NCOL + dirOff;
    float4 w0 = *(const float4*)(up + jg*8);
    float4 w1 = *(const float4*)(up + jg*8 + 4);
    wg[kk][0]=w0.x; wg[kk][1]=w0.y; wg[kk][2]=w0.z; wg[kk][3]=w0.w;
    wg[kk][4]=w1.x; wg[kk][5]=w1.y; wg[kk][6]=w1.z; wg[kk][7]=w1.w;
    float4 wv = *(const float4*)(up + 256 + jg*4);
    wc[kk][0]=wv.x; wc[kk][1]=wv.y; wc[kk][2]=wv.z; wc[kk][3]=wv.w;
  }
  float bias_g = bias[dirOff + tid];
  float bias_c = (tid < 128) ? bias[dirOff + 256 + tid] : 0.f;

  if (tid < 128) h_s[tid] = 0.f;
  __syncthreads();

  // prefetch step 0's x-projection
  int pos0 = dir ? (L - 1) : 0;
  int tok0 = seq[pos0];
  const float* xr0 = proj + (size_t)tok0 * NCOL + dirOff;
  float xg = xr0[tid];
  float xc = (tid < 128) ? xr0[256 + tid] : 0.f;

  for (int t = 0; t < L; ++t) {
    // prefetch next step (hidden behind compute)
    float xg_n = 0.f, xc_n = 0.f;
    if (t + 1 < L) {
      int pos_n = dir ? (L - 2 - t) : (t + 1);
      int tok_n = seq[pos_n];
      const float* xr = proj + (size_t)tok_n * NCOL + dirOff;
      xg_n = xr[tid];
      xc_n = (tid < 128) ? xr[256 + tid] : 0.f;
    }

    // phase 1: gate partials (h broadcast reads; 8 acc chains for ILP)
    float a[8] = {0.f,0.f,0.f,0.f,0.f,0.f,0.f,0.f};
    const float4* h4 = (const float4*)h_s;
#pragma unroll
    for (int q = 0; q < 4; ++q) {
      float4 hv = h4[kg*4 + q];
      float he[4] = {hv.x, hv.y, hv.z, hv.w};
#pragma unroll
      for (int e = 0; e < 4; ++e)
#pragma unroll
        for (int jj = 0; jj < 8; ++jj)
          a[jj] += he[e] * wg[q*4 + e][jj];
    }
    *(float4*)(&pg[kg][jg*8])     = make_float4(a[0], a[1], a[2], a[3]);
    *(float4*)(&pg[kg][jg*8 + 4]) = make_float4(a[4], a[5], a[6], a[7]);
    __syncthreads();   // B1

    // gate consume: column tid
    float g = xg + bias_g;
#pragma unroll
    for (int k2 = 0; k2 < 8; ++k2) g += pg[k2][tid];
    g = fast_sigmoid(g);

    float h_old = 0.f;
    if (tid < 128) { h_old = h_s[tid]; rh_s[tid] = g * h_old; }
    else           { u_s[tid - 128] = g; }
    __syncthreads();   // B2

    // phase 2: cand partials
    float ac[4] = {0.f, 0.f, 0.f, 0.f};
    const float4* rh4 = (const float4*)rh_s;
#pragma unroll
    for (int q = 0; q < 4; ++q) {
      float4 rv = rh4[kg*4 + q];
      float re[4] = {rv.x, rv.y, rv.z, rv.w};
#pragma unroll
      for (int e = 0; e < 4; ++e)
#pragma unroll
        for (int jj = 0; jj < 4; ++jj)
          ac[jj] += re[e] * wc[q*4 + e][jj];
    }
    *(float4*)(&pc[kg][jg*4]) = make_float4(ac[0], ac[1], ac[2], ac[3]);
    __syncthreads();   // B3

    // cand consume + h update
    if (tid < 128) {
      float cs = xc + bias_c;
#pragma unroll
      for (int k2 = 0; k2 < 8; ++k2) cs += pc[k2][tid];
      float c = fast_tanh(cs);
      float u = u_s[tid];
      float hn = u * h_old + (1.f - u) * c;
      h_s[tid] = hn;
      int pos = dir ? (L - 1 - t) : t;
      stbase[(size_t)pos * C_ + tid] = hn;
    }
    __syncthreads();   // B4
    xg = xg_n; xc = xc_n;
  }

  // zero tail rows [L, S) — replaces the global memset of states
  for (int i = L * C_ + tid; i < S * C_; i += 256) stbase[i] = 0.f;
}

// ---------------------------------------------------------------------------
// Attention: one WG per (b, array); flash-style online softmax.
// ---------------------------------------------------------------------------
__global__ __launch_bounds__(256, 2) void attn_kernel(
    const float* __restrict__ states, const float* __restrict__ att_v,
    const float* __restrict__ att_w, const float* __restrict__ att_b,
    float* __restrict__ feats) {
  __shared__ __align__(16) float st_s[8][132];
  __shared__ __align__(16) float pgA[8][8][132];
  __shared__ float score_s[8];
  __shared__ float cm[128], cl[128], ca[128];

  int bid = blockIdx.x, tid = threadIdx.x;
  int b, dir, S, featOff; const float* stb;
  if (bid < 256) {
    b = bid >> 1; dir = bid & 1; S = SC_;
    stb = states + (dir ? SZ_ST_CTX : 0) + (size_t)b * SC_ * C_;
    featOff = dir * 128;
  } else {
    int q = bid - 256; b = q >> 1; dir = q & 1; S = SE_;
    stb = states + 2*SZ_ST_CTX + (dir ? SZ_ST_END : 0) + (size_t)b * SE_ * C_;
    featOff = 256 + dir * 128;
  }

  int kg = tid >> 5, jg = tid & 31;
  float wreg[16][4];
#pragma unroll
  for (int kk = 0; kk < 16; ++kk) {
    float4 wv = *(const float4*)(att_w + (size_t)(kg*16 + kk) * C_ + jg*4);
    wreg[kk][0]=wv.x; wreg[kk][1]=wv.y; wreg[kk][2]=wv.z; wreg[kk][3]=wv.w;
  }
  int d0 = jg * 4;
  float4 b4 = *(const float4*)(att_b + d0);
  float4 v4 = *(const float4*)(att_v + d0);
  int c = tid & 127, half = tid >> 7;

  float m = -1e30f, lsum = 0.f, acc = 0.f;

  for (int s0 = 0; s0 < S; s0 += 8) {
    __syncthreads();
    for (int lId = tid; lId < 1024; lId += 256) {
      int r = lId >> 7, k = lId & 127;
      st_s[r][k] = stb[(size_t)(s0 + r) * C_ + k];
    }
    __syncthreads();

    float pacc[8][4] = {};
#pragma unroll
    for (int r = 0; r < 8; ++r) {
      const float4* srow4 = (const float4*)(&st_s[r][0]);
#pragma unroll
      for (int q = 0; q < 4; ++q) {
        float4 sv = srow4[kg*4 + q];
        float se[4] = {sv.x, sv.y, sv.z, sv.w};
#pragma unroll
        for (int e = 0; e < 4; ++e)
#pragma unroll
          for (int jj = 0; jj < 4; ++jj)
            pacc[r][jj] += se[e] * wreg[q*4 + e][jj];
      }
    }
#pragma unroll
    for (int r = 0; r < 8; ++r)
      *(float4*)(&pgA[kg][r][jg*4]) =
          make_float4(pacc[r][0], pacc[r][1], pacc[r][2], pacc[r][3]);
    __syncthreads();

    float4 p4 = make_float4(0.f, 0.f, 0.f, 0.f);
#pragma unroll
    for (int k2 = 0; k2 < 8; ++k2) {
      float4 t4 = *(const float4*)(&pgA[k2][kg][d0]);
      p4.x += t4.x; p4.y += t4.y; p4.z += t4.z; p4.w += t4.w;
    }
    float sc = tanhf(p4.x + b4.x) * v4.x + tanhf(p4.y + b4.y) * v4.y +
               tanhf(p4.z + b4.z) * v4.z + tanhf(p4.w + b4.w) * v4.w;
#pragma unroll
    for (int off = 16; off > 0; off >>= 1) sc += __shfl_xor(sc, off, 64);
    if (jg == 0) score_s[kg] = sc;
    __syncthreads();

    float srow[8]; float smax = m;
#pragma unroll
    for (int r = 0; r < 8; ++r) { srow[r] = score_s[r]; smax = fmaxf(smax, srow[r]); }
    float scale = expf(m - smax);
    acc *= scale; lsum *= scale; m = smax;
#pragma unroll
    for (int rr = 0; rr < 4; ++rr) {
      int r = half * 4 + rr;
      float w = expf(srow[r] - m);
      lsum += w;
      acc += w * st_s[r][c];
    }
  }

  __syncthreads();
  if (half == 1) { cm[c] = m; cl[c] = lsum; ca[c] = acc; }
  __syncthreads();
  if (half == 0) {
    float m1 = cm[c], l1 = cl[c], a1 = ca[c];
    float M = fmaxf(m, m1);
    float w0 = expf(m - M), w1 = expf(m1 - M);
    feats[b * 512 + featOff + c] = (acc * w0 + a1 * w1) / (lsum * w0 + l1 * w1);
  }
}

// ---------------------------------------------------------------------------
// Head
// ---------------------------------------------------------------------------
__global__ __launch_bounds__(128) void head_kernel(
    const float* __restrict__ feats, const float* __restrict__ hid_w,
    const float* __restrict__ hid_b, const float* __restrict__ out_w,
    const float* __restrict__ out_b, float* __restrict__ out) {
  __shared__ __align__(16) float f_s[512];
  __shared__ float part[2];
  int b = blockIdx.x, tid = threadIdx.x;
  for (int i = tid; i < 512; i += 128) f_s[i] = feats[b * 512 + i];
  __syncthreads();
  float h = hid_b[tid];
  for (int k = 0; k < 512; ++k) h += f_s[k] * hid_w[k * 128 + tid];
  h = fmaxf(h, 0.f);
  float p = h * out_w[tid];
#pragma unroll
  for (int off = 32; off > 0; off >>= 1) p += __shfl_xor(p, off, 64);
  if ((tid & 63) == 0) part[tid >> 6] = p;
  __syncthreads();
  if (tid == 0) out[b] = part[0] + part[1] + out_b[0];
}

// ---------------------------------------------------------------------------
extern "C" void kernel_launch(void* const* d_in, const int* in_sizes, int n_in,
                              void* d_out, int out_size, void* d_ws, size_t ws_size,
                              hipStream_t stream) {
  const int*   ctx     = (const int*)d_in[0];
  const int*   endseq  = (const int*)d_in[1];
  const int*   ctx_len = (const int*)d_in[2];
  const int*   end_len = (const int*)d_in[3];
  const float* emb     = (const float*)d_in[4];
  const float* fw_gw   = (const float*)d_in[5];
  const float* fw_gb   = (const float*)d_in[6];
  const float* fw_cw   = (const float*)d_in[7];
  const float* fw_cb   = (const float*)d_in[8];
  const float* bw_gw   = (const float*)d_in[9];
  const float* bw_gb   = (const float*)d_in[10];
  const float* bw_cw   = (const float*)d_in[11];
  const float* bw_cb   = (const float*)d_in[12];
  const float* att_v   = (const float*)d_in[13];
  const float* att_w   = (const float*)d_in[14];
  const float* att_b   = (const float*)d_in[15];
  const float* hid_w   = (const float*)d_in[16];
  const float* hid_b   = (const float*)d_in[17];
  const float* out_w   = (const float*)d_in[18];
  const float* out_b   = (const float*)d_in[19];
  float* ws  = (float*)d_ws;
  float* out = (float*)d_out;

  short* Ahi  = (short*)(ws + OFF_ST);
  short* Alo  = Ahi + (size_t)V_ * KP;
  short* Bthi = (short*)(ws + OFF_BT);
  short* Btlo = Bthi + (size_t)NCOL * KP;

  pack_kernel<<<1299, 256, 0, stream>>>(fw_gw, fw_gb, fw_cw, fw_cb,
                                        bw_gw, bw_gb, bw_cw, bw_cb, ws);
  pack_bt<<<(NCOL * KP + 255) / 256, 256, 0, stream>>>(ws + OFF_WXP, Bthi, Btlo);
  pack_emb<<<(int)(((size_t)V_ * KP + 255) / 256), 256, 0, stream>>>(emb, Ahi, Alo);

  dim3 ggrid(6, 391);
  gemm_mfma<<<ggrid, 256, 0, stream>>>(Ahi, Alo, Bthi, Btlo, ws + OFF_PROJ);

  recur_kernel<<<512, 256, 0, stream>>>(ctx, endseq, ctx_len, end_len,
                                        ws + OFF_PROJ, ws + OFF_UALL,
                                        ws + OFF_BIAS, ws + OFF_ST);

  attn_kernel<<<512, 256, 0, stream>>>(ws + OFF_ST, att_v, att_w, att_b,
                                       ws + OFF_FEATS);

  head_kernel<<<128, 128, 0, stream>>>(ws + OFF_FEATS, hid_w, hid_b,
                                       out_w, out_b, out);
}